// Round 1
// baseline (843.711 us; speedup 1.0000x reference)
//
#include <hip/hip_runtime.h>
#include <cfloat>
#include <math.h>

#define N_SAMP 32768
#define FF 8
#define HU 128
#define LL 32
#define EE 1024
#define VV 2048
#define PP 320
#define SIGLEN 584
#define FINAL_W 9344

__device__ __forceinline__ double wave_red(double v) {
#pragma unroll
  for (int off = 32; off > 0; off >>= 1) v += __shfl_xor(v, off, 64);
  return v;
}

// ---------------- stats of eigenvalues (for input-layer BN closed form) -------------
__global__ __launch_bounds__(256) void k_xstats(const float* __restrict__ x,
                                                double* __restrict__ xst) {
  const int tid = threadIdx.x;
  double s1 = 0.0, s2 = 0.0;
  for (int i = tid; i < N_SAMP; i += 256) { double v = (double)x[i]; s1 += v; s2 += v * v; }
  __shared__ double r1[4], r2[4];
  double w1 = wave_red(s1), w2 = wave_red(s2);
  int wave = tid >> 6, lane = tid & 63;
  if (lane == 0) { r1[wave] = w1; r2[wave] = w2; }
  __syncthreads();
  if (tid == 0) {
    xst[0] = r1[0] + r1[1] + r1[2] + r1[3];
    xst[1] = r2[0] + r2[1] + r2[2] + r2[3];
  }
}

// ---------------- hidden-layer GEMM + fused BN/ReLU on input + column stats ---------
// MODE 0: A generated from scalar x via folded input-layer BN (h1 = relu(x*p0 + p1))
// MODE 1: A = relu(Yin * sc + sh)  (BN of previous layer applied on load), in-place OK
template<int MODE>
__global__ __launch_bounds__(256, 2)
void k_gemm(const float* __restrict__ Ain,          // MODE0: x[N]; MODE1: Y[F][N][HU]
            const double* __restrict__ xstats,      // MODE0 only
            const float* __restrict__ w_in,         // MODE0: Win [F][HU]
            const float* __restrict__ g_in,         // MODE0: gin
            const float* __restrict__ beta_in,      // MODE0: betain
            const float* __restrict__ sc,           // MODE1: [F][HU]
            const float* __restrict__ sh,
            const float* __restrict__ Wb, int wstride,
            const float* __restrict__ bb, int bstride,
            float* __restrict__ Yout,
            double* __restrict__ stats) {
  __shared__ float As[32][132];
  __shared__ float Bs[32][132];
  __shared__ float p0[HU], p1[HU], biasl[HU], xl[HU];
  const int tid = threadIdx.x;
  const int f = blockIdx.y;
  const int m0 = blockIdx.x * 128;

  if (tid < HU) {
    biasl[tid] = bb[(size_t)f * bstride + tid];
    if (MODE == 0) {
      double mx = xstats[0] * (1.0 / 32768.0);
      double vx = xstats[1] * (1.0 / 32768.0) - mx * mx;
      if (vx < 0) vx = 0;
      float w = w_in[f * HU + tid];
      double inv = 1.0 / sqrt((double)w * (double)w * vx + 1e-5);
      float sj = (float)inv * g_in[f * HU + tid] * w;
      p0[tid] = sj;
      p1[tid] = beta_in[f * HU + tid] - (float)mx * sj;
      xl[tid] = Ain[m0 + tid];
    } else {
      p0[tid] = sc[f * HU + tid];
      p1[tid] = sh[f * HU + tid];
    }
  }

  float cacc[8][8];
#pragma unroll
  for (int i = 0; i < 8; ++i)
#pragma unroll
    for (int j = 0; j < 8; ++j) cacc[i][j] = 0.f;

  const int tidm = tid & 15, tidn = tid >> 4;

  for (int kk = 0; kk < 128; kk += 32) {
    __syncthreads();
    if (MODE == 0) {
#pragma unroll
      for (int r = 0; r < 16; ++r) {
        int flat = tid + r * 256;
        int k = flat >> 7, m = flat & 127;
        As[k][m] = fmaxf(fmaf(xl[m], p0[kk + k], p1[kk + k]), 0.f);
      }
    } else {
#pragma unroll
      for (int r = 0; r < 4; ++r) {
        int flat = tid + r * 256;
        int m = flat >> 3, kf = flat & 7;
        const float4 yv = *(const float4*)(Ain + ((size_t)(f * N_SAMP) + m0 + m) * HU + kk + kf * 4);
        As[kf * 4 + 0][m] = fmaxf(fmaf(yv.x, p0[kk + kf * 4 + 0], p1[kk + kf * 4 + 0]), 0.f);
        As[kf * 4 + 1][m] = fmaxf(fmaf(yv.y, p0[kk + kf * 4 + 1], p1[kk + kf * 4 + 1]), 0.f);
        As[kf * 4 + 2][m] = fmaxf(fmaf(yv.z, p0[kk + kf * 4 + 2], p1[kk + kf * 4 + 2]), 0.f);
        As[kf * 4 + 3][m] = fmaxf(fmaf(yv.w, p0[kk + kf * 4 + 3], p1[kk + kf * 4 + 3]), 0.f);
      }
    }
#pragma unroll
    for (int r = 0; r < 4; ++r) {
      int flat = tid + r * 256;
      int n = flat >> 3, kf = flat & 7;
      const float4 wv = *(const float4*)(Wb + (size_t)f * wstride + n * HU + kk + kf * 4);
      Bs[kf * 4 + 0][n] = wv.x;
      Bs[kf * 4 + 1][n] = wv.y;
      Bs[kf * 4 + 2][n] = wv.z;
      Bs[kf * 4 + 3][n] = wv.w;
    }
    __syncthreads();
#pragma unroll
    for (int k = 0; k < 32; ++k) {
      float4 a0 = *(const float4*)&As[k][tidm * 8];
      float4 a1 = *(const float4*)&As[k][tidm * 8 + 4];
      float4 b0 = *(const float4*)&Bs[k][tidn * 8];
      float4 b1 = *(const float4*)&Bs[k][tidn * 8 + 4];
      float av[8] = {a0.x, a0.y, a0.z, a0.w, a1.x, a1.y, a1.z, a1.w};
      float bv[8] = {b0.x, b0.y, b0.z, b0.w, b1.x, b1.y, b1.z, b1.w};
#pragma unroll
      for (int i = 0; i < 8; ++i)
#pragma unroll
        for (int j = 0; j < 8; ++j) cacc[i][j] = fmaf(av[i], bv[j], cacc[i][j]);
    }
  }
  __syncthreads();

  float cs1[8], cs2[8];
#pragma unroll
  for (int j = 0; j < 8; ++j) { cs1[j] = 0.f; cs2[j] = 0.f; }
#pragma unroll
  for (int i = 0; i < 8; ++i) {
    int row = m0 + tidm * 8 + i;
    float out[8];
#pragma unroll
    for (int j = 0; j < 8; ++j) {
      float v = cacc[i][j] + biasl[tidn * 8 + j];
      out[j] = v;
      cs1[j] += v;
      cs2[j] = fmaf(v, v, cs2[j]);
    }
    float4* dst = (float4*)(Yout + ((size_t)(f * N_SAMP) + row) * HU + tidn * 8);
    dst[0] = make_float4(out[0], out[1], out[2], out[3]);
    dst[1] = make_float4(out[4], out[5], out[6], out[7]);
  }
  float* red1 = &As[0][0];   // 2048 floats needed, 4224 available
  float* red2 = &Bs[0][0];
#pragma unroll
  for (int j = 0; j < 8; ++j) red1[tidm * 128 + tidn * 8 + j] = cs1[j];
#pragma unroll
  for (int j = 0; j < 8; ++j) red2[tidm * 128 + tidn * 8 + j] = cs2[j];
  __syncthreads();
  {
    int which = tid >> 7, n = tid & 127;
    const float* rp = which ? red2 : red1;
    float s = 0.f;
#pragma unroll
    for (int r = 0; r < 16; ++r) s += rp[r * 128 + n];
    atomicAdd(&stats[(f * HU + n) * 2 + which], (double)s);
  }
}

// ---------------- finalize BN affine params from accumulated stats ------------------
__global__ __launch_bounds__(256) void k_fin(const double* __restrict__ stats,
                                             const float* __restrict__ g,
                                             const float* __restrict__ beta,
                                             int per_f, int gstride, int count,
                                             float* __restrict__ sc, float* __restrict__ sh) {
  int idx = blockIdx.x * 256 + threadIdx.x;
  if (idx >= count) return;
  int f = idx / per_f, j = idx - f * per_f;
  double S1 = stats[idx * 2 + 0], S2 = stats[idx * 2 + 1];
  double mean = S1 * (1.0 / 32768.0);
  double var = S2 * (1.0 / 32768.0) - mean * mean;
  if (var < 0) var = 0;
  double inv = 1.0 / sqrt(var + 1e-5);
  float gg = g[f * gstride + j];
  float scv = (float)inv * gg;
  sc[idx] = scv;
  sh[idx] = beta[f * gstride + j] - (float)mean * scv;
}

// ---------------- output layer (128 -> 1) + stats ----------------------------------
__global__ __launch_bounds__(256) void k_outlayer(const float* __restrict__ Y,
                                                  const float* __restrict__ sc2,
                                                  const float* __restrict__ sh2,
                                                  const float* __restrict__ Wout,
                                                  const float* __restrict__ bout,
                                                  float* __restrict__ evs_pre,
                                                  double* __restrict__ stats3) {
  __shared__ float wj[HU], scl[HU], shl[HU];
  const int tid = threadIdx.x;
  const int f = blockIdx.y;
  const int i = blockIdx.x * 256 + tid;
  if (tid < HU) {
    wj[tid] = Wout[f * HU + tid];
    scl[tid] = sc2[f * HU + tid];
    shl[tid] = sh2[f * HU + tid];
  }
  __syncthreads();
  const float4* base = (const float4*)(Y + ((size_t)(f * N_SAMP) + i) * HU);
  float acc = 0.f;
#pragma unroll
  for (int q = 0; q < 32; ++q) {
    float4 y = base[q];
    int j = q * 4;
    acc = fmaf(fmaxf(fmaf(y.x, scl[j + 0], shl[j + 0]), 0.f), wj[j + 0], acc);
    acc = fmaf(fmaxf(fmaf(y.y, scl[j + 1], shl[j + 1]), 0.f), wj[j + 1], acc);
    acc = fmaf(fmaxf(fmaf(y.z, scl[j + 2], shl[j + 2]), 0.f), wj[j + 2], acc);
    acc = fmaf(fmaxf(fmaf(y.w, scl[j + 3], shl[j + 3]), 0.f), wj[j + 3], acc);
  }
  float yo = acc + bout[f];
  evs_pre[(size_t)f * N_SAMP + i] = yo;
  double v = (double)yo;
  double s1 = wave_red(v), s2 = wave_red(v * v);
  __shared__ double r1[4], r2[4];
  int wave = tid >> 6, lane = tid & 63;
  if (lane == 0) { r1[wave] = s1; r2[wave] = s2; }
  __syncthreads();
  if (tid == 0) atomicAdd(&stats3[f * 2 + 0], r1[0] + r1[1] + r1[2] + r1[3]);
  if (tid == 1) atomicAdd(&stats3[f * 2 + 1], r2[0] + r2[1] + r2[2] + r2[3]);
}

// ---------------- einsum lfv: fv[l,f,v] = sum_e evs[f,l,e] * eig[l,e,v] -------------
__global__ __launch_bounds__(256) void k_einsum(const float* __restrict__ evs_pre,
                                                const float* __restrict__ sc3,
                                                const float* __restrict__ sh3,
                                                const float* __restrict__ eig,
                                                float* __restrict__ fv) {
  __shared__ float ev[FF * EE];
  const int tid = threadIdx.x;
  const int l = blockIdx.y;
  const int v0 = blockIdx.x * 256;
#pragma unroll
  for (int r = 0; r < 32; ++r) {
    int q = tid + r * 256;
    int f = q >> 10, e = q & 1023;
    float y = evs_pre[(size_t)f * N_SAMP + l * EE + e];
    ev[q] = fmaxf(fmaf(y, sc3[f], sh3[f]), 0.f);
  }
  __syncthreads();
  const float* up = eig + (size_t)l * EE * VV + v0 + tid;
  float acc[8] = {0, 0, 0, 0, 0, 0, 0, 0};
  for (int e0 = 0; e0 < EE; e0 += 16) {
    float u[16];
#pragma unroll
    for (int t = 0; t < 16; ++t) u[t] = up[(size_t)(e0 + t) * VV];
#pragma unroll
    for (int t = 0; t < 16; ++t) {
#pragma unroll
      for (int f = 0; f < 8; ++f) acc[f] = fmaf(ev[f * EE + e0 + t], u[t], acc[f]);
    }
  }
#pragma unroll
  for (int f = 0; f < 8; ++f) fv[((size_t)(l * FF + f)) * VV + v0 + tid] = acc[f];
}

// ---------------- per-diagram: gather, project, sort, level-3 signature -------------
__global__ __launch_bounds__(256) void k_diagram(const float* __restrict__ fv,
                                                 const int* __restrict__ dgm0,
                                                 const int* __restrict__ dgm1rel,
                                                 const int* __restrict__ dgm1ext,
                                                 const float* __restrict__ Wp,
                                                 const float* __restrict__ bp,
                                                 float* __restrict__ xbuf) {
  __shared__ float vals[640];
  __shared__ float ps[7 * 512];
  __shared__ float dXl[320][8];
  const int tid = threadIdx.x;
  const int bid = blockIdx.x;
  const int row = bid >> 1;
  const int c = bid & 1;
  const float* fvr = fv + (size_t)row * VV;

  for (int k = tid; k < 640; k += 256) {
    int idx;
    if (c == 0) idx = (k < 512) ? dgm0[(size_t)row * 512 + k] : dgm1rel[(size_t)row * 129 + (640 - k)];
    else        idx = dgm1ext[(size_t)row * 640 + k];
    vals[k] = fvr[idx];
  }
  __syncthreads();
  for (int q = tid; q < 7 * 512; q += 256) {
    int s = q >> 9, p = q & 511;
    float pv = 3.402823466e+38f;
    if (p < PP) pv = fmaf(Wp[2 * s + 1], vals[2 * p + 1], fmaf(Wp[2 * s], vals[2 * p], bp[s]));
    ps[s * 512 + p] = pv;
  }
  // bitonic sort each of the 7 rows (padded to 512 with +FLT_MAX), ascending
  for (int k = 2; k <= 512; k <<= 1) {
    for (int j = k >> 1; j > 0; j >>= 1) {
      __syncthreads();
      for (int q = tid; q < 1792; q += 256) {
        int s = q >> 8, ip = q & 255;
        int i = ((ip & ~(j - 1)) << 1) | (ip & (j - 1));
        int p2 = i | j;
        float a = ps[s * 512 + i], b = ps[s * 512 + p2];
        bool up = ((i & k) == 0);
        if ((a > b) == up) { ps[s * 512 + i] = b; ps[s * 512 + p2] = a; }
      }
    }
  }
  __syncthreads();
  for (int q = tid; q < 319 * 8; q += 256) {
    int p = q >> 3, d = q & 7;
    dXl[p][d] = (d == 0) ? (1.0f / 51360.0f)
                         : ps[(d - 1) * 512 + p + 1] - ps[(d - 1) * 512 + p];
  }
  __syncthreads();
  if (tid < 64) {
    const int a = tid >> 3, b = tid & 7;
    float s1a = 0.f, s2r = 0.f;
    float s3r[8] = {0, 0, 0, 0, 0, 0, 0, 0};
    for (int p = 0; p < 319; ++p) {
      float4 dlo = *(const float4*)&dXl[p][0];
      float4 dhi = *(const float4*)&dXl[p][4];
      float dxa = dXl[p][a];
      float dxb = dXl[p][b];
      // r3_abc = s3 + dx_c * [ (s1_a + dx_a/3)*(dx_b/2) + s2_ab ]
      float coefA = fmaf(dxa, (1.f / 3.f), s1a);
      float w = fmaf(0.5f * dxb, coefA, s2r);
      // r2_ab = s2 + (dx_a/2 + s1_a)*dx_b   (uses old s1)
      s2r = fmaf(dxb, fmaf(0.5f, dxa, s1a), s2r);
      s3r[0] = fmaf(w, dlo.x, s3r[0]);
      s3r[1] = fmaf(w, dlo.y, s3r[1]);
      s3r[2] = fmaf(w, dlo.z, s3r[2]);
      s3r[3] = fmaf(w, dlo.w, s3r[3]);
      s3r[4] = fmaf(w, dhi.x, s3r[4]);
      s3r[5] = fmaf(w, dhi.y, s3r[5]);
      s3r[6] = fmaf(w, dhi.z, s3r[6]);
      s3r[7] = fmaf(w, dhi.w, s3r[7]);
      s1a += dxa;
    }
    const int l = row >> 3, ff = row & 7;
    float* xr = xbuf + (size_t)l * FINAL_W + ff * (2 * SIGLEN) + c * SIGLEN;
    if ((tid & 7) == 0) xr[a] = s1a;     // lanes b==0 hold s1 for their a
    xr[8 + tid] = s2r;                   // s2[a*8+b] at flat index tid
    float* s3p = xr + 72 + tid * 8;      // s3[a*64+b*8+c] = flat 8*tid + c
    *(float4*)(s3p + 0) = make_float4(s3r[0], s3r[1], s3r[2], s3r[3]);
    *(float4*)(s3p + 4) = make_float4(s3r[4], s3r[5], s3r[6], s3r[7]);
  }
}

// ---------------- final 9344-dot per l (fp64) --------------------------------------
__global__ __launch_bounds__(256) void k_rowdot(const float* __restrict__ xbuf,
                                                const float* __restrict__ Wf,
                                                const float* __restrict__ bf,
                                                double* __restrict__ outpre) {
  const int tid = threadIdx.x, l = blockIdx.x;
  const float* xr = xbuf + (size_t)l * FINAL_W;
  double acc = 0.0;
  for (int k = tid; k < FINAL_W; k += 256) acc += (double)xr[k] * (double)Wf[k];
  acc = wave_red(acc);
  __shared__ double r[4];
  int wave = tid >> 6, lane = tid & 63;
  if (lane == 0) r[wave] = acc;
  __syncthreads();
  if (tid == 0) outpre[l] = r[0] + r[1] + r[2] + r[3] + (double)bf[0];
}

// ---------------- final BN over 32 samples (fp64, eps-dominated) --------------------
__global__ __launch_bounds__(64) void k_bnfin(const double* __restrict__ outpre,
                                              const float* __restrict__ g,
                                              const float* __restrict__ beta,
                                              float* __restrict__ dout) {
  int i = threadIdx.x;
  double v = (i < 32) ? outpre[i] : 0.0;
  double s1 = wave_red(v);
  double s2 = wave_red(v * v);
  double mean = s1 * (1.0 / 32.0);
  double var = s2 * (1.0 / 32.0) - mean * mean;
  if (var < 0) var = 0;
  double inv = 1.0 / sqrt(var + 1e-5);
  if (i < 32) dout[i] = (float)((v - mean) * inv * (double)g[0] + (double)beta[0]);
}

extern "C" void kernel_launch(void* const* d_in, const int* in_sizes, int n_in,
                              void* d_out, int out_size, void* d_ws, size_t ws_size,
                              hipStream_t stream) {
  const float* eig     = (const float*)d_in[0];
  const float* eigsq   = (const float*)d_in[1];
  const int*   dgm0    = (const int*)d_in[2];
  const int*   dgm1rel = (const int*)d_in[3];
  const int*   dgm1ext = (const int*)d_in[4];
  const float* Win     = (const float*)d_in[5];
  // d_in[6] = mlp_bin: cancels exactly in input-layer BN
  const float* gin     = (const float*)d_in[7];
  const float* betain  = (const float*)d_in[8];
  const float* Wh      = (const float*)d_in[9];
  const float* bh      = (const float*)d_in[10];
  const float* gh      = (const float*)d_in[11];
  const float* betah   = (const float*)d_in[12];
  const float* Wout    = (const float*)d_in[13];
  const float* bout    = (const float*)d_in[14];
  const float* gout    = (const float*)d_in[15];
  const float* betaout = (const float*)d_in[16];
  const float* Wp      = (const float*)d_in[17];
  const float* bp      = (const float*)d_in[18];
  const float* Wfin    = (const float*)d_in[19];
  const float* bfin    = (const float*)d_in[20];
  const float* gfin    = (const float*)d_in[21];
  const float* betafin = (const float*)d_in[22];

  char* ws = (char*)d_ws;
  float*  Y       = (float*)(ws);                  // 134,217,728 B : [F][N][HU], reused in-place
  float*  evs_pre = (float*)(ws + 134217728u);     //   1,048,576 B : [F][N]
  float*  fv      = (float*)(ws + 135266304u);     //   2,097,152 B : [L*F][V]
  float*  xbuf    = (float*)(ws + 137363456u);     //   1,196,032 B : [L][9344]
  float*  sc1     = (float*)(ws + 138559488u);     // BN affine params
  float*  sh1     = sc1 + 1024;
  float*  sc2     = sc1 + 2048;
  float*  sh2     = sc1 + 3072;
  float*  sc3     = sc1 + 4096;
  float*  sh3     = sc1 + 4160;
  double* stats1  = (double*)(ws + 138576384u);    // [F*HU][2]
  double* stats2  = stats1 + 2048;                 // [F*HU][2]
  double* stats3  = stats1 + 4096;                 // [F][2]
  double* xstats  = stats1 + 4112;                 // [2]
  double* outpre  = stats1 + 4114;                 // [32]

  // zero the atomically-accumulated stats (ws is poisoned each call)
  hipMemsetAsync(stats1, 0, 4114 * sizeof(double), stream);

  k_xstats<<<1, 256, 0, stream>>>(eig, xstats);
  // hidden layer 0: Y = relu_bn_in(x) @ Wh0^T + bh0, stats1
  k_gemm<0><<<dim3(256, FF), 256, 0, stream>>>(eig, xstats, Win, gin, betain,
                                               nullptr, nullptr,
                                               Wh, 32768, bh, 256, Y, stats1);
  k_fin<<<4, 256, 0, stream>>>(stats1, gh, betah, 128, 256, 1024, sc1, sh1);
  // hidden layer 1: Y = relu_bn1(Y) @ Wh1^T + bh1 (in-place), stats2
  k_gemm<1><<<dim3(256, FF), 256, 0, stream>>>(Y, nullptr, nullptr, nullptr, nullptr,
                                               sc1, sh1,
                                               Wh + 16384, 32768, bh + 128, 256, Y, stats2);
  k_fin<<<4, 256, 0, stream>>>(stats2, gh + 128, betah + 128, 128, 256, 1024, sc2, sh2);
  // output layer
  k_outlayer<<<dim3(128, FF), 256, 0, stream>>>(Y, sc2, sh2, Wout, bout, evs_pre, stats3);
  k_fin<<<1, 256, 0, stream>>>(stats3, gout, betaout, 1, 1, 8, sc3, sh3);
  // einsum lfv
  k_einsum<<<dim3(8, 32), 256, 0, stream>>>(evs_pre, sc3, sh3, eigsq, fv);
  // diagrams: 512 = 256 rows x {Dgm0, Dgm1}
  k_diagram<<<512, 256, 0, stream>>>(fv, dgm0, dgm1rel, dgm1ext, Wp, bp, xbuf);
  // final linear + BN over L=32
  k_rowdot<<<32, 256, 0, stream>>>(xbuf, Wfin, bfin, outpre);
  k_bnfin<<<1, 64, 0, stream>>>(outpre, gfin, betafin, (float*)d_out);
}

// Round 2
// 806.242 us; speedup vs baseline: 1.0465x; 1.0465x over previous
//
#include <hip/hip_runtime.h>
#include <cfloat>
#include <math.h>

#define N_SAMP 32768
#define FF 8
#define HU 128
#define LL 32
#define EE 1024
#define VV 2048
#define PP 320
#define SIGLEN 584
#define FINAL_W 9344

// swizzled in-row position for GEMM LDS fragments:
// element m of a k-row stored at (m&4)<<4 | (m>>3)<<2 | (m&3)
// -> a-frag float4 reads by 16 lanes are 64 contiguous floats (2-way banks = free)
__device__ __forceinline__ int frag_pos(int m) {
  return ((m & 4) << 4) | ((m >> 3) << 2) | (m & 3);
}

__device__ __forceinline__ double wave_red(double v) {
#pragma unroll
  for (int off = 32; off > 0; off >>= 1) v += __shfl_xor(v, off, 64);
  return v;
}

// ---------------- stats of eigenvalues (for input-layer BN closed form) -------------
__global__ __launch_bounds__(256) void k_xstats(const float* __restrict__ x,
                                                double* __restrict__ xst) {
  const int tid = threadIdx.x;
  double s1 = 0.0, s2 = 0.0;
  for (int i = tid; i < N_SAMP; i += 256) { double v = (double)x[i]; s1 += v; s2 += v * v; }
  __shared__ double r1[4], r2[4];
  double w1 = wave_red(s1), w2 = wave_red(s2);
  int wave = tid >> 6, lane = tid & 63;
  if (lane == 0) { r1[wave] = w1; r2[wave] = w2; }
  __syncthreads();
  if (tid == 0) {
    xst[0] = r1[0] + r1[1] + r1[2] + r1[3];
    xst[1] = r2[0] + r2[1] + r2[2] + r2[3];
  }
}

// ---------------- hidden-layer GEMM + fused BN/ReLU on input + column stats ---------
// Computes Yt[f][j][m] = sum_k A[m,k] * W[j,k] + b[j]   (TRANSPOSED output)
// MODE 0: A generated from scalar x via folded input-layer BN (a = relu(x*p0 + p1))
// MODE 1: A = relu(Yt_in[f][k][m] * sc[k] + sh[k])  (BN of prev layer on load), in-place OK
template<int MODE>
__global__ __launch_bounds__(256, 4)
void k_gemm(const float* __restrict__ Ain,          // MODE0: x[N]; MODE1: Yt[F][HU][N]
            const double* __restrict__ xstats,      // MODE0 only
            const float* __restrict__ w_in,         // MODE0: Win [F][HU]
            const float* __restrict__ g_in,         // MODE0: gin
            const float* __restrict__ beta_in,      // MODE0: betain
            const float* __restrict__ sc,           // MODE1: [F][HU]
            const float* __restrict__ sh,
            const float* __restrict__ Wb, int wstride,
            const float* __restrict__ bb, int bstride,
            float* __restrict__ Yt_out,
            double* __restrict__ stats) {
  __shared__ __align__(16) float As[32][132];
  __shared__ __align__(16) float Bs[32][132];
  __shared__ __align__(16) float p0[HU], p1[HU], biasl[HU], xl[HU];
  const int tid = threadIdx.x;
  const int f = blockIdx.y;
  const int m0 = blockIdx.x * 128;

  if (tid < HU) {
    biasl[tid] = bb[(size_t)f * bstride + tid];
    if (MODE == 0) {
      double mx = xstats[0] * (1.0 / 32768.0);
      double vx = xstats[1] * (1.0 / 32768.0) - mx * mx;
      if (vx < 0) vx = 0;
      float w = w_in[f * HU + tid];
      double inv = 1.0 / sqrt((double)w * (double)w * vx + 1e-5);
      float sj = (float)inv * g_in[f * HU + tid] * w;
      p0[tid] = sj;
      p1[tid] = beta_in[f * HU + tid] - (float)mx * sj;
      xl[tid] = Ain[m0 + tid];
    } else {
      p0[tid] = sc[f * HU + tid];
      p1[tid] = sh[f * HU + tid];
    }
  }

  float cacc[8][8];
#pragma unroll
  for (int i = 0; i < 8; ++i)
#pragma unroll
    for (int j = 0; j < 8; ++j) cacc[i][j] = 0.f;

  const int tidm = tid & 15, tidn = tid >> 4;

  for (int kk = 0; kk < 128; kk += 32) {
    __syncthreads();
    // ---- stage A chunk [32 k][128 m] into swizzled layout, float4 granularity ----
#pragma unroll
    for (int r = 0; r < 4; ++r) {
      int flat4 = tid + r * 256;           // 0..1023
      int k = flat4 >> 5;                  // 0..31
      int mc = flat4 & 31;                 // float4-chunk: m = mc*4..mc*4+3
      int pos = ((mc & 1) << 6) | ((mc >> 1) << 2);
      float a0, a1, a2, a3;
      if (MODE == 0) {
        const float4 xv = *(const float4*)&xl[mc * 4];
        float s = p0[kk + k], t = p1[kk + k];
        a0 = fmaxf(fmaf(xv.x, s, t), 0.f);
        a1 = fmaxf(fmaf(xv.y, s, t), 0.f);
        a2 = fmaxf(fmaf(xv.z, s, t), 0.f);
        a3 = fmaxf(fmaf(xv.w, s, t), 0.f);
      } else {
        const float4 yv = *(const float4*)(Ain + ((size_t)(f * HU + kk + k)) * N_SAMP + m0 + mc * 4);
        float s = p0[kk + k], t = p1[kk + k];
        a0 = fmaxf(fmaf(yv.x, s, t), 0.f);
        a1 = fmaxf(fmaf(yv.y, s, t), 0.f);
        a2 = fmaxf(fmaf(yv.z, s, t), 0.f);
        a3 = fmaxf(fmaf(yv.w, s, t), 0.f);
      }
      *(float4*)&As[k][pos] = make_float4(a0, a1, a2, a3);
    }
    // ---- stage B chunk: Bs[k][n] = W[n][kk+k], scalar transpose writes (small) ----
#pragma unroll
    for (int r = 0; r < 4; ++r) {
      int flat = tid + r * 256;
      int n = flat >> 3, kf = flat & 7;
      const float4 wv = *(const float4*)(Wb + (size_t)f * wstride + n * HU + kk + kf * 4);
      int pn = frag_pos(n);
      Bs[kf * 4 + 0][pn] = wv.x;
      Bs[kf * 4 + 1][pn] = wv.y;
      Bs[kf * 4 + 2][pn] = wv.z;
      Bs[kf * 4 + 3][pn] = wv.w;
    }
    __syncthreads();
#pragma unroll
    for (int k = 0; k < 32; ++k) {
      float4 a0 = *(const float4*)&As[k][tidm * 4];
      float4 a1 = *(const float4*)&As[k][64 + tidm * 4];
      float4 b0 = *(const float4*)&Bs[k][tidn * 4];
      float4 b1 = *(const float4*)&Bs[k][64 + tidn * 4];
      float av[8] = {a0.x, a0.y, a0.z, a0.w, a1.x, a1.y, a1.z, a1.w};
      float bv[8] = {b0.x, b0.y, b0.z, b0.w, b1.x, b1.y, b1.z, b1.w};
#pragma unroll
      for (int i = 0; i < 8; ++i)
#pragma unroll
        for (int j = 0; j < 8; ++j) cacc[i][j] = fmaf(av[i], bv[j], cacc[i][j]);
    }
  }
  __syncthreads();

  // ---- epilogue: add bias, write TRANSPOSED, accumulate column stats ----
  float cs1[8], cs2[8];
#pragma unroll
  for (int j = 0; j < 8; ++j) { cs1[j] = 0.f; cs2[j] = 0.f; }
#pragma unroll
  for (int jj = 0; jj < 8; ++jj) {
    int j = tidn * 8 + jj;
    float b = biasl[j];
    float o[8];
#pragma unroll
    for (int i = 0; i < 8; ++i) {
      float v = cacc[i][jj] + b;
      o[i] = v;
      cs1[jj] += v;
      cs2[jj] = fmaf(v, v, cs2[jj]);
    }
    float* dst = Yt_out + ((size_t)(f * HU + j)) * N_SAMP + m0 + tidm * 8;
    *(float4*)dst = make_float4(o[0], o[1], o[2], o[3]);
    *(float4*)(dst + 4) = make_float4(o[4], o[5], o[6], o[7]);
  }
  float* red1 = &As[0][0];   // 2048 floats needed, 4224 available
  float* red2 = &Bs[0][0];
#pragma unroll
  for (int j = 0; j < 8; ++j) red1[tidm * 128 + tidn * 8 + j] = cs1[j];
#pragma unroll
  for (int j = 0; j < 8; ++j) red2[tidm * 128 + tidn * 8 + j] = cs2[j];
  __syncthreads();
  {
    int which = tid >> 7, n = tid & 127;
    const float* rp = which ? red2 : red1;
    float s = 0.f;
#pragma unroll
    for (int r = 0; r < 16; ++r) s += rp[r * 128 + n];
    atomicAdd(&stats[(f * HU + n) * 2 + which], (double)s);
  }
}

// ---------------- finalize BN affine params from accumulated stats ------------------
__global__ __launch_bounds__(256) void k_fin(const double* __restrict__ stats,
                                             const float* __restrict__ g,
                                             const float* __restrict__ beta,
                                             int per_f, int gstride, int count,
                                             float* __restrict__ sc, float* __restrict__ sh) {
  int idx = blockIdx.x * 256 + threadIdx.x;
  if (idx >= count) return;
  int f = idx / per_f, j = idx - f * per_f;
  double S1 = stats[idx * 2 + 0], S2 = stats[idx * 2 + 1];
  double mean = S1 * (1.0 / 32768.0);
  double var = S2 * (1.0 / 32768.0) - mean * mean;
  if (var < 0) var = 0;
  double inv = 1.0 / sqrt(var + 1e-5);
  float gg = g[f * gstride + j];
  float scv = (float)inv * gg;
  sc[idx] = scv;
  sh[idx] = beta[f * gstride + j] - (float)mean * scv;
}

// ---------------- output layer (128 -> 1) + stats, reads TRANSPOSED Yt --------------
__global__ __launch_bounds__(256, 4) void k_outlayer(const float* __restrict__ Yt,
                                                     const float* __restrict__ sc2,
                                                     const float* __restrict__ sh2,
                                                     const float* __restrict__ Wout,
                                                     const float* __restrict__ bout,
                                                     float* __restrict__ evs_pre,
                                                     double* __restrict__ stats3) {
  __shared__ float wj[HU], scl[HU], shl[HU];
  const int tid = threadIdx.x;
  const int f = blockIdx.y;
  const int i = blockIdx.x * 256 + tid;
  if (tid < HU) {
    wj[tid] = Wout[f * HU + tid];
    scl[tid] = sc2[f * HU + tid];
    shl[tid] = sh2[f * HU + tid];
  }
  __syncthreads();
  const float* base = Yt + (size_t)f * HU * N_SAMP + i;
  float acc = 0.f;
#pragma unroll
  for (int j = 0; j < HU; ++j) {
    float y = base[(size_t)j * N_SAMP];
    acc = fmaf(fmaxf(fmaf(y, scl[j], shl[j]), 0.f), wj[j], acc);
  }
  float yo = acc + bout[f];
  evs_pre[(size_t)f * N_SAMP + i] = yo;
  double v = (double)yo;
  double s1 = wave_red(v), s2 = wave_red(v * v);
  __shared__ double r1[4], r2[4];
  int wave = tid >> 6, lane = tid & 63;
  if (lane == 0) { r1[wave] = s1; r2[wave] = s2; }
  __syncthreads();
  if (tid == 0) atomicAdd(&stats3[f * 2 + 0], r1[0] + r1[1] + r1[2] + r1[3]);
  if (tid == 1) atomicAdd(&stats3[f * 2 + 1], r2[0] + r2[1] + r2[2] + r2[3]);
}

// ---------------- einsum lfv: fv[l,f,v] = sum_e evs[f,l,e] * eig[l,e,v] -------------
__global__ __launch_bounds__(256) void k_einsum(const float* __restrict__ evs_pre,
                                                const float* __restrict__ sc3,
                                                const float* __restrict__ sh3,
                                                const float* __restrict__ eig,
                                                float* __restrict__ fv) {
  __shared__ float ev[FF * EE];
  const int tid = threadIdx.x;
  const int l = blockIdx.y;
  const int v0 = blockIdx.x * 256;
#pragma unroll
  for (int r = 0; r < 32; ++r) {
    int q = tid + r * 256;
    int f = q >> 10, e = q & 1023;
    float y = evs_pre[(size_t)f * N_SAMP + l * EE + e];
    ev[q] = fmaxf(fmaf(y, sc3[f], sh3[f]), 0.f);
  }
  __syncthreads();
  const float* up = eig + (size_t)l * EE * VV + v0 + tid;
  float acc[8] = {0, 0, 0, 0, 0, 0, 0, 0};
  for (int e0 = 0; e0 < EE; e0 += 32) {
    float u[32];
#pragma unroll
    for (int t = 0; t < 32; ++t) u[t] = up[(size_t)(e0 + t) * VV];
#pragma unroll
    for (int t = 0; t < 32; ++t) {
#pragma unroll
      for (int f = 0; f < 8; ++f) acc[f] = fmaf(ev[f * EE + e0 + t], u[t], acc[f]);
    }
  }
#pragma unroll
  for (int f = 0; f < 8; ++f) fv[((size_t)(l * FF + f)) * VV + v0 + tid] = acc[f];
}

// ---------------- per-diagram: gather, project, sort, level-3 signature -------------
__global__ __launch_bounds__(256) void k_diagram(const float* __restrict__ fv,
                                                 const int* __restrict__ dgm0,
                                                 const int* __restrict__ dgm1rel,
                                                 const int* __restrict__ dgm1ext,
                                                 const float* __restrict__ Wp,
                                                 const float* __restrict__ bp,
                                                 float* __restrict__ xbuf) {
  __shared__ float vals[640];
  __shared__ float ps[7 * 512];
  __shared__ float dXl[320][8];
  const int tid = threadIdx.x;
  const int bid = blockIdx.x;
  const int row = bid >> 1;
  const int c = bid & 1;
  const float* fvr = fv + (size_t)row * VV;

  for (int k = tid; k < 640; k += 256) {
    int idx;
    if (c == 0) idx = (k < 512) ? dgm0[(size_t)row * 512 + k] : dgm1rel[(size_t)row * 129 + (640 - k)];
    else        idx = dgm1ext[(size_t)row * 640 + k];
    vals[k] = fvr[idx];
  }
  __syncthreads();
  for (int q = tid; q < 7 * 512; q += 256) {
    int s = q >> 9, p = q & 511;
    float pv = 3.402823466e+38f;
    if (p < PP) pv = fmaf(Wp[2 * s + 1], vals[2 * p + 1], fmaf(Wp[2 * s], vals[2 * p], bp[s]));
    ps[s * 512 + p] = pv;
  }
  // bitonic sort each of the 7 rows (padded to 512 with +FLT_MAX), ascending
  for (int k = 2; k <= 512; k <<= 1) {
    for (int j = k >> 1; j > 0; j >>= 1) {
      __syncthreads();
      for (int q = tid; q < 1792; q += 256) {
        int s = q >> 8, ip = q & 255;
        int i = ((ip & ~(j - 1)) << 1) | (ip & (j - 1));
        int p2 = i | j;
        float a = ps[s * 512 + i], b = ps[s * 512 + p2];
        bool up = ((i & k) == 0);
        if ((a > b) == up) { ps[s * 512 + i] = b; ps[s * 512 + p2] = a; }
      }
    }
  }
  __syncthreads();
  for (int q = tid; q < 319 * 8; q += 256) {
    int p = q >> 3, d = q & 7;
    dXl[p][d] = (d == 0) ? (1.0f / 51360.0f)
                         : ps[(d - 1) * 512 + p + 1] - ps[(d - 1) * 512 + p];
  }
  __syncthreads();
  if (tid < 64) {
    const int a = tid >> 3, b = tid & 7;
    float s1a = 0.f, s2r = 0.f;
    float s3r[8] = {0, 0, 0, 0, 0, 0, 0, 0};
    for (int p = 0; p < 319; ++p) {
      float4 dlo = *(const float4*)&dXl[p][0];
      float4 dhi = *(const float4*)&dXl[p][4];
      float dxa = dXl[p][a];
      float dxb = dXl[p][b];
      // r3_abc = s3 + dx_c * [ (s1_a + dx_a/3)*(dx_b/2) + s2_ab ]
      float coefA = fmaf(dxa, (1.f / 3.f), s1a);
      float w = fmaf(0.5f * dxb, coefA, s2r);
      // r2_ab = s2 + (dx_a/2 + s1_a)*dx_b   (uses old s1)
      s2r = fmaf(dxb, fmaf(0.5f, dxa, s1a), s2r);
      s3r[0] = fmaf(w, dlo.x, s3r[0]);
      s3r[1] = fmaf(w, dlo.y, s3r[1]);
      s3r[2] = fmaf(w, dlo.z, s3r[2]);
      s3r[3] = fmaf(w, dlo.w, s3r[3]);
      s3r[4] = fmaf(w, dhi.x, s3r[4]);
      s3r[5] = fmaf(w, dhi.y, s3r[5]);
      s3r[6] = fmaf(w, dhi.z, s3r[6]);
      s3r[7] = fmaf(w, dhi.w, s3r[7]);
      s1a += dxa;
    }
    const int l = row >> 3, ff = row & 7;
    float* xr = xbuf + (size_t)l * FINAL_W + ff * (2 * SIGLEN) + c * SIGLEN;
    if ((tid & 7) == 0) xr[a] = s1a;     // lanes b==0 hold s1 for their a
    xr[8 + tid] = s2r;                   // s2[a*8+b] at flat index tid
    float* s3p = xr + 72 + tid * 8;      // s3[a*64+b*8+c] = flat 8*tid + c
    *(float4*)(s3p + 0) = make_float4(s3r[0], s3r[1], s3r[2], s3r[3]);
    *(float4*)(s3p + 4) = make_float4(s3r[4], s3r[5], s3r[6], s3r[7]);
  }
}

// ---------------- final 9344-dot per l (fp64) --------------------------------------
__global__ __launch_bounds__(256) void k_rowdot(const float* __restrict__ xbuf,
                                                const float* __restrict__ Wf,
                                                const float* __restrict__ bf,
                                                double* __restrict__ outpre) {
  const int tid = threadIdx.x, l = blockIdx.x;
  const float* xr = xbuf + (size_t)l * FINAL_W;
  double acc = 0.0;
  for (int k = tid; k < FINAL_W; k += 256) acc += (double)xr[k] * (double)Wf[k];
  acc = wave_red(acc);
  __shared__ double r[4];
  int wave = tid >> 6, lane = tid & 63;
  if (lane == 0) r[wave] = acc;
  __syncthreads();
  if (tid == 0) outpre[l] = r[0] + r[1] + r[2] + r[3] + (double)bf[0];
}

// ---------------- final BN over 32 samples (fp64, eps-dominated) --------------------
__global__ __launch_bounds__(64) void k_bnfin(const double* __restrict__ outpre,
                                              const float* __restrict__ g,
                                              const float* __restrict__ beta,
                                              float* __restrict__ dout) {
  int i = threadIdx.x;
  double v = (i < 32) ? outpre[i] : 0.0;
  double s1 = wave_red(v);
  double s2 = wave_red(v * v);
  double mean = s1 * (1.0 / 32.0);
  double var = s2 * (1.0 / 32.0) - mean * mean;
  if (var < 0) var = 0;
  double inv = 1.0 / sqrt(var + 1e-5);
  if (i < 32) dout[i] = (float)((v - mean) * inv * (double)g[0] + (double)beta[0]);
}

extern "C" void kernel_launch(void* const* d_in, const int* in_sizes, int n_in,
                              void* d_out, int out_size, void* d_ws, size_t ws_size,
                              hipStream_t stream) {
  const float* eig     = (const float*)d_in[0];
  const float* eigsq   = (const float*)d_in[1];
  const int*   dgm0    = (const int*)d_in[2];
  const int*   dgm1rel = (const int*)d_in[3];
  const int*   dgm1ext = (const int*)d_in[4];
  const float* Win     = (const float*)d_in[5];
  // d_in[6] = mlp_bin: cancels exactly in input-layer BN
  const float* gin     = (const float*)d_in[7];
  const float* betain  = (const float*)d_in[8];
  const float* Wh      = (const float*)d_in[9];
  const float* bh      = (const float*)d_in[10];
  const float* gh      = (const float*)d_in[11];
  const float* betah   = (const float*)d_in[12];
  const float* Wout    = (const float*)d_in[13];
  const float* bout    = (const float*)d_in[14];
  const float* gout    = (const float*)d_in[15];
  const float* betaout = (const float*)d_in[16];
  const float* Wp      = (const float*)d_in[17];
  const float* bp      = (const float*)d_in[18];
  const float* Wfin    = (const float*)d_in[19];
  const float* bfin    = (const float*)d_in[20];
  const float* gfin    = (const float*)d_in[21];
  const float* betafin = (const float*)d_in[22];

  char* ws = (char*)d_ws;
  float*  Yt      = (float*)(ws);                  // 134,217,728 B : [F][HU][N], in-place reuse
  float*  evs_pre = (float*)(ws + 134217728u);     //   1,048,576 B : [F][N]
  float*  fv      = (float*)(ws + 135266304u);     //   2,097,152 B : [L*F][V]
  float*  xbuf    = (float*)(ws + 137363456u);     //   1,196,032 B : [L][9344]
  float*  sc1     = (float*)(ws + 138559488u);     // BN affine params
  float*  sh1     = sc1 + 1024;
  float*  sc2     = sc1 + 2048;
  float*  sh2     = sc1 + 3072;
  float*  sc3     = sc1 + 4096;
  float*  sh3     = sc1 + 4160;
  double* stats1  = (double*)(ws + 138576384u);    // [F*HU][2]
  double* stats2  = stats1 + 2048;                 // [F*HU][2]
  double* stats3  = stats1 + 4096;                 // [F][2]
  double* xstats  = stats1 + 4112;                 // [2]
  double* outpre  = stats1 + 4114;                 // [32]

  // zero the atomically-accumulated stats (ws is poisoned each call)
  hipMemsetAsync(stats1, 0, 4114 * sizeof(double), stream);

  k_xstats<<<1, 256, 0, stream>>>(eig, xstats);
  // hidden layer 0: Yt = (relu_bn_in(x) @ Wh0^T)^T + bh0, stats1
  k_gemm<0><<<dim3(256, FF), 256, 0, stream>>>(eig, xstats, Win, gin, betain,
                                               nullptr, nullptr,
                                               Wh, 32768, bh, 256, Yt, stats1);
  k_fin<<<4, 256, 0, stream>>>(stats1, gh, betah, 128, 256, 1024, sc1, sh1);
  // hidden layer 1: Yt = (relu_bn1(Yt) @ Wh1^T)^T + bh1 (in-place), stats2
  k_gemm<1><<<dim3(256, FF), 256, 0, stream>>>(Yt, nullptr, nullptr, nullptr, nullptr,
                                               sc1, sh1,
                                               Wh + 16384, 32768, bh + 128, 256, Yt, stats2);
  k_fin<<<4, 256, 0, stream>>>(stats2, gh + 128, betah + 128, 128, 256, 1024, sc2, sh2);
  // output layer
  k_outlayer<<<dim3(128, FF), 256, 0, stream>>>(Yt, sc2, sh2, Wout, bout, evs_pre, stats3);
  k_fin<<<1, 256, 0, stream>>>(stats3, gout, betaout, 1, 1, 8, sc3, sh3);
  // einsum lfv
  k_einsum<<<dim3(8, 32), 256, 0, stream>>>(evs_pre, sc3, sh3, eigsq, fv);
  // diagrams: 512 = 256 rows x {Dgm0, Dgm1}
  k_diagram<<<512, 256, 0, stream>>>(fv, dgm0, dgm1rel, dgm1ext, Wp, bp, xbuf);
  // final linear + BN over L=32
  k_rowdot<<<32, 256, 0, stream>>>(xbuf, Wfin, bfin, outpre);
  k_bnfin<<<1, 64, 0, stream>>>(outpre, gfin, betafin, (float*)d_out);
}

// Round 3
// 743.809 us; speedup vs baseline: 1.1343x; 1.0839x over previous
//
#include <hip/hip_runtime.h>
#include <cfloat>
#include <math.h>

#define N_SAMP 32768
#define FF 8
#define HU 128
#define EE 1024
#define VV 2048
#define PP 320
#define SIGLEN 584
#define FINAL_W 9344

typedef unsigned short u16;
typedef unsigned int u32;
typedef short s16x8 __attribute__((ext_vector_type(8)));
typedef float f32x4 __attribute__((ext_vector_type(4)));

__device__ __forceinline__ u16 f2bf(float v) {
  u32 u = __float_as_uint(v);
  return (u16)((u + 0x7fffu + ((u >> 16) & 1u)) >> 16);
}
__device__ __forceinline__ float bf2f(u16 h) {
  return __uint_as_float(((u32)h) << 16);
}
// split v = hi + mid + lo (+ residual <= ~2^-25 |v|)
__device__ __forceinline__ void split3(float v, u16& h, u16& m, u16& l) {
  h = f2bf(v);
  float r = v - bf2f(h);
  m = f2bf(r);
  float r2 = r - bf2f(m);
  l = f2bf(r2);
}

__device__ __forceinline__ double wave_red(double v) {
#pragma unroll
  for (int off = 32; off > 0; off >>= 1) v += __shfl_xor(v, off, 64);
  return v;
}

// ---------------- split W into 3 bf16 limb arrays ----------------------------------
__global__ __launch_bounds__(256) void k_wsplit(const float* __restrict__ W,
                                                u16* __restrict__ Hh, u16* __restrict__ Hm,
                                                u16* __restrict__ Hl, int n) {
  int i = blockIdx.x * 256 + threadIdx.x;
  if (i >= n) return;
  u16 h, m, l;
  split3(W[i], h, m, l);
  Hh[i] = h; Hm[i] = m; Hl[i] = l;
}

// ---------------- stats of eigenvalues (for input-layer BN closed form) -------------
__global__ __launch_bounds__(256) void k_xstats(const float* __restrict__ x,
                                                double* __restrict__ xst) {
  const int tid = threadIdx.x;
  double s1 = 0.0, s2 = 0.0;
  for (int i = tid; i < N_SAMP; i += 256) { double v = (double)x[i]; s1 += v; s2 += v * v; }
  __shared__ double r1[4], r2[4];
  double w1 = wave_red(s1), w2 = wave_red(s2);
  int wave = tid >> 6, lane = tid & 63;
  if (lane == 0) { r1[wave] = w1; r2[wave] = w2; }
  __syncthreads();
  if (tid == 0) {
    xst[0] = r1[0] + r1[1] + r1[2] + r1[3];
    xst[1] = r2[0] + r2[1] + r2[2] + r2[3];
  }
}

// ---------------- MFMA hidden-layer GEMM, bf16 3-split x 6 passes -------------------
// Yt[f][j][m] = sum_k A[m,k] W[j,k] + b[j]  (transposed out), plus column stats.
// MODE 0: A[m,k] = relu(x_m * p0_k + p1_k)   (folded input-layer BN)
// MODE 1: A[m,k] = relu(Yt_in[f][k][m] * sc_k + sh_k)  (in-place safe: disjoint cols)
template<int MODE>
__global__ __launch_bounds__(256, 2)
void k_mgemm(const float* __restrict__ Ain,       // MODE0: x[N]; MODE1: Yt[F][HU][N]
             const double* __restrict__ xstats,   // MODE0
             const float* __restrict__ w_in,      // MODE0: Win [F][HU]
             const float* __restrict__ g_in,
             const float* __restrict__ beta_in,
             const float* __restrict__ sc,        // MODE1: [F][HU]
             const float* __restrict__ sh,
             const u16* __restrict__ Wh_,         // [F][HU][HU] bf16 limbs (layer pre-offset)
             const u16* __restrict__ Wm_,
             const u16* __restrict__ Wl_,
             const float* __restrict__ bb, int bstride,
             float* __restrict__ Yt_out,
             double* __restrict__ stats) {
  // 6 staging buffers: rows of 32 k-limbs padded to 40 (80 B: 16-B aligned, 2-way banks)
  __shared__ u16 SB[6][128 * 40];
  __shared__ float p0[HU], p1[HU], biasl[HU], xl[HU];
  u16* Ah = SB[0]; u16* Am = SB[1]; u16* Al = SB[2];
  u16* Bh = SB[3]; u16* Bm = SB[4]; u16* Bl = SB[5];

  const int tid = threadIdx.x;
  const int f = blockIdx.y;
  const int m0 = blockIdx.x * 128;
  const int lane = tid & 63, ln = tid & 15, quad = (tid >> 4) & 3, wave = tid >> 6;

  if (tid < HU) {
    biasl[tid] = bb[(size_t)f * bstride + tid];
    if (MODE == 0) {
      double mx = xstats[0] * (1.0 / 32768.0);
      double vx = xstats[1] * (1.0 / 32768.0) - mx * mx;
      if (vx < 0) vx = 0;
      float w = w_in[f * HU + tid];
      double inv = 1.0 / sqrt((double)w * (double)w * vx + 1e-5);
      float sj = (float)inv * g_in[f * HU + tid] * w;
      p0[tid] = sj;
      p1[tid] = beta_in[f * HU + tid] - (float)mx * sj;
      xl[tid] = Ain[m0 + tid];
    } else {
      p0[tid] = sc[f * HU + tid];
      p1[tid] = sh[f * HU + tid];
    }
  }

  f32x4 acc[2][8];
#pragma unroll
  for (int mt = 0; mt < 2; ++mt)
#pragma unroll
    for (int u = 0; u < 8; ++u) acc[mt][u] = (f32x4){0.f, 0.f, 0.f, 0.f};

  __syncthreads();

  for (int kk = 0; kk < 128; kk += 32) {
    // ---- stage A chunk [128 m][32 k] as 3 bf16 limbs, layout [m][k] ----
    if (MODE == 0) {
      const int m = tid >> 1, kh = (tid & 1) * 16;
      const float xv = xl[m];
      u32 ph[8], pm[8], pl[8];
#pragma unroll
      for (int jp = 0; jp < 8; ++jp) {
        u16 h0, m_0, l0, h1, m_1, l1;
        int k = kh + jp * 2;
        split3(fmaxf(fmaf(xv, p0[kk + k], p1[kk + k]), 0.f), h0, m_0, l0);
        split3(fmaxf(fmaf(xv, p0[kk + k + 1], p1[kk + k + 1]), 0.f), h1, m_1, l1);
        ph[jp] = (u32)h0 | ((u32)h1 << 16);
        pm[jp] = (u32)m_0 | ((u32)m_1 << 16);
        pl[jp] = (u32)l0 | ((u32)l1 << 16);
      }
      int off = m * 40 + kh;  // u16 index; byte = 80m + 2kh (32-B aligned)
      *(uint4*)&Ah[off] = make_uint4(ph[0], ph[1], ph[2], ph[3]);
      *(uint4*)&Ah[off + 8] = make_uint4(ph[4], ph[5], ph[6], ph[7]);
      *(uint4*)&Am[off] = make_uint4(pm[0], pm[1], pm[2], pm[3]);
      *(uint4*)&Am[off + 8] = make_uint4(pm[4], pm[5], pm[6], pm[7]);
      *(uint4*)&Al[off] = make_uint4(pl[0], pl[1], pl[2], pl[3]);
      *(uint4*)&Al[off + 8] = make_uint4(pl[4], pl[5], pl[6], pl[7]);
    } else {
#pragma unroll
      for (int r = 0; r < 4; ++r) {
        int flat = tid + r * 256;           // 0..1023
        int m = flat & 127, kq = flat >> 7; // kq 0..7 -> k = kq*4..+3
        const float* src = Ain + ((size_t)(f * HU + kk + kq * 4)) * N_SAMP + m0 + m;
        u32 ph[2], pm[2], pl[2];
#pragma unroll
        for (int ip = 0; ip < 2; ++ip) {
          int k = kq * 4 + ip * 2;
          float v0 = fmaxf(fmaf(src[(size_t)(ip * 2) * N_SAMP], p0[kk + k], p1[kk + k]), 0.f);
          float v1 = fmaxf(fmaf(src[(size_t)(ip * 2 + 1) * N_SAMP], p0[kk + k + 1], p1[kk + k + 1]), 0.f);
          u16 h0, m_0, l0, h1, m_1, l1;
          split3(v0, h0, m_0, l0);
          split3(v1, h1, m_1, l1);
          ph[ip] = (u32)h0 | ((u32)h1 << 16);
          pm[ip] = (u32)m_0 | ((u32)m_1 << 16);
          pl[ip] = (u32)l0 | ((u32)l1 << 16);
        }
        int off = m * 40 + kq * 4;  // byte = 80m + 8kq (8-B aligned)
        *(uint2*)&Ah[off] = make_uint2(ph[0], ph[1]);
        *(uint2*)&Am[off] = make_uint2(pm[0], pm[1]);
        *(uint2*)&Al[off] = make_uint2(pl[0], pl[1]);
      }
    }
    // ---- stage B chunk [128 n][32 k] from pre-split W limbs ----
#pragma unroll
    for (int r = 0; r < 2; ++r) {
      int flat = tid + r * 256;          // 0..511
      int n = flat >> 2, c = flat & 3;   // 16-B chunk c of the 64-B k-row piece
      size_t g = (size_t)f * (2 * HU * HU) + (size_t)n * HU + kk + c * 8;
      int off = n * 40 + c * 8;
      *(uint4*)&Bh[off] = *(const uint4*)&Wh_[g];
      *(uint4*)&Bm[off] = *(const uint4*)&Wm_[g];
      *(uint4*)&Bl[off] = *(const uint4*)&Wl_[g];
    }
    __syncthreads();
    // ---- MFMA: 2 m-tiles x 8 n-tiles x 6 limb passes ----
    s16x8 af0[3], af1[3];
    {
      int r0 = (wave * 32 + ln) * 40 + quad * 8;
      int r1 = (wave * 32 + 16 + ln) * 40 + quad * 8;
      af0[0] = *(const s16x8*)&Ah[r0]; af0[1] = *(const s16x8*)&Am[r0]; af0[2] = *(const s16x8*)&Al[r0];
      af1[0] = *(const s16x8*)&Ah[r1]; af1[1] = *(const s16x8*)&Am[r1]; af1[2] = *(const s16x8*)&Al[r1];
    }
#pragma unroll
    for (int u = 0; u < 8; ++u) {
      int bo = (u * 16 + ln) * 40 + quad * 8;
      s16x8 bh = *(const s16x8*)&Bh[bo];
      s16x8 bm = *(const s16x8*)&Bm[bo];
      s16x8 bl = *(const s16x8*)&Bl[bo];
      f32x4 a0 = acc[0][u], a1 = acc[1][u];
      a0 = __builtin_amdgcn_mfma_f32_16x16x32_bf16(af0[0], bh, a0, 0, 0, 0);
      a1 = __builtin_amdgcn_mfma_f32_16x16x32_bf16(af1[0], bh, a1, 0, 0, 0);
      a0 = __builtin_amdgcn_mfma_f32_16x16x32_bf16(af0[1], bh, a0, 0, 0, 0);
      a1 = __builtin_amdgcn_mfma_f32_16x16x32_bf16(af1[1], bh, a1, 0, 0, 0);
      a0 = __builtin_amdgcn_mfma_f32_16x16x32_bf16(af0[0], bm, a0, 0, 0, 0);
      a1 = __builtin_amdgcn_mfma_f32_16x16x32_bf16(af1[0], bm, a1, 0, 0, 0);
      a0 = __builtin_amdgcn_mfma_f32_16x16x32_bf16(af0[2], bh, a0, 0, 0, 0);
      a1 = __builtin_amdgcn_mfma_f32_16x16x32_bf16(af1[2], bh, a1, 0, 0, 0);
      a0 = __builtin_amdgcn_mfma_f32_16x16x32_bf16(af0[1], bm, a0, 0, 0, 0);
      a1 = __builtin_amdgcn_mfma_f32_16x16x32_bf16(af1[1], bm, a1, 0, 0, 0);
      a0 = __builtin_amdgcn_mfma_f32_16x16x32_bf16(af0[0], bl, a0, 0, 0, 0);
      a1 = __builtin_amdgcn_mfma_f32_16x16x32_bf16(af1[0], bl, a1, 0, 0, 0);
      acc[0][u] = a0; acc[1][u] = a1;
    }
    __syncthreads();
  }

  // ---- epilogue: bias, column stats, direct transposed float4 stores ----
  // C layout: n = u*16+ln (fixed per lane), m = wave*32 + mt*16 + quad*4 + reg
  // -> each lane's f32x4 is 4 consecutive m in one n-row: one coalesced float4 store.
  float cs1[8], cs2[8];
#pragma unroll
  for (int u = 0; u < 8; ++u) { cs1[u] = 0.f; cs2[u] = 0.f; }
#pragma unroll
  for (int u = 0; u < 8; ++u) {
    float b = biasl[u * 16 + ln];
#pragma unroll
    for (int mt = 0; mt < 2; ++mt) {
#pragma unroll
      for (int reg = 0; reg < 4; ++reg) {
        float v = acc[mt][u][reg] + b;
        acc[mt][u][reg] = v;
        cs1[u] += v;
        cs2[u] = fmaf(v, v, cs2[u]);
      }
      float4 st = make_float4(acc[mt][u][0], acc[mt][u][1], acc[mt][u][2], acc[mt][u][3]);
      *(float4*)&Yt_out[((size_t)(f * HU + u * 16 + ln)) * N_SAMP + m0 + wave * 32 + mt * 16 + quad * 4] = st;
    }
  }
  float* red1 = (float*)&SB[0][0];
  float* red2 = red1 + 2048;
  int wq = wave * 4 + quad;
#pragma unroll
  for (int u = 0; u < 8; ++u) {
    red1[wq * 128 + u * 16 + ln] = cs1[u];
    red2[wq * 128 + u * 16 + ln] = cs2[u];
  }
  __syncthreads();
  {
    int which = tid >> 7, n = tid & 127;
    const float* rp = which ? red2 : red1;
    float s = 0.f;
#pragma unroll
    for (int r = 0; r < 16; ++r) s += rp[r * 128 + n];
    atomicAdd(&stats[(f * HU + n) * 2 + which], (double)s);
  }
}

// ---------------- finalize BN affine params from accumulated stats ------------------
__global__ __launch_bounds__(256) void k_fin(const double* __restrict__ stats,
                                             const float* __restrict__ g,
                                             const float* __restrict__ beta,
                                             int per_f, int gstride, int count,
                                             float* __restrict__ sc, float* __restrict__ sh) {
  int idx = blockIdx.x * 256 + threadIdx.x;
  if (idx >= count) return;
  int f = idx / per_f, j = idx - f * per_f;
  double S1 = stats[idx * 2 + 0], S2 = stats[idx * 2 + 1];
  double mean = S1 * (1.0 / 32768.0);
  double var = S2 * (1.0 / 32768.0) - mean * mean;
  if (var < 0) var = 0;
  double inv = 1.0 / sqrt(var + 1e-5);
  float gg = g[f * gstride + j];
  float scv = (float)inv * gg;
  sc[idx] = scv;
  sh[idx] = beta[f * gstride + j] - (float)mean * scv;
}

// ---------------- output layer (128 -> 1) + stats, reads TRANSPOSED Yt --------------
__global__ __launch_bounds__(256, 4) void k_outlayer(const float* __restrict__ Yt,
                                                     const float* __restrict__ sc2,
                                                     const float* __restrict__ sh2,
                                                     const float* __restrict__ Wout,
                                                     const float* __restrict__ bout,
                                                     float* __restrict__ evs_pre,
                                                     double* __restrict__ stats3) {
  __shared__ float wj[HU], scl[HU], shl[HU];
  const int tid = threadIdx.x;
  const int f = blockIdx.y;
  const int i = blockIdx.x * 256 + tid;
  if (tid < HU) {
    wj[tid] = Wout[f * HU + tid];
    scl[tid] = sc2[f * HU + tid];
    shl[tid] = sh2[f * HU + tid];
  }
  __syncthreads();
  const float* base = Yt + (size_t)f * HU * N_SAMP + i;
  float acc = 0.f;
#pragma unroll
  for (int j = 0; j < HU; ++j) {
    float y = base[(size_t)j * N_SAMP];
    acc = fmaf(fmaxf(fmaf(y, scl[j], shl[j]), 0.f), wj[j], acc);
  }
  float yo = acc + bout[f];
  evs_pre[(size_t)f * N_SAMP + i] = yo;
  double v = (double)yo;
  double s1 = wave_red(v), s2 = wave_red(v * v);
  __shared__ double r1[4], r2[4];
  int wave = tid >> 6, lane = tid & 63;
  if (lane == 0) { r1[wave] = s1; r2[wave] = s2; }
  __syncthreads();
  if (tid == 0) atomicAdd(&stats3[f * 2 + 0], r1[0] + r1[1] + r1[2] + r1[3]);
  if (tid == 1) atomicAdd(&stats3[f * 2 + 1], r2[0] + r2[1] + r2[2] + r2[3]);
}

// ---------------- einsum lfv: fv[l,f,v] = sum_e evs[f,l,e] * eig[l,e,v] -------------
__global__ __launch_bounds__(256) void k_einsum(const float* __restrict__ evs_pre,
                                                const float* __restrict__ sc3,
                                                const float* __restrict__ sh3,
                                                const float* __restrict__ eig,
                                                float* __restrict__ fv) {
  __shared__ float ev[FF * EE];
  const int tid = threadIdx.x;
  const int l = blockIdx.y;
  const int v0 = blockIdx.x * 256;
#pragma unroll
  for (int r = 0; r < 32; ++r) {
    int q = tid + r * 256;
    int f = q >> 10, e = q & 1023;
    float y = evs_pre[(size_t)f * N_SAMP + l * EE + e];
    ev[q] = fmaxf(fmaf(y, sc3[f], sh3[f]), 0.f);
  }
  __syncthreads();
  const float* up = eig + (size_t)l * EE * VV + v0 + tid;
  float acc[8] = {0, 0, 0, 0, 0, 0, 0, 0};
  for (int e0 = 0; e0 < EE; e0 += 32) {
    float u[32];
#pragma unroll
    for (int t = 0; t < 32; ++t) u[t] = up[(size_t)(e0 + t) * VV];
#pragma unroll
    for (int t = 0; t < 32; ++t) {
#pragma unroll
      for (int f = 0; f < 8; ++f) acc[f] = fmaf(ev[f * EE + e0 + t], u[t], acc[f]);
    }
  }
#pragma unroll
  for (int f = 0; f < 8; ++f) fv[((size_t)(l * FF + f)) * VV + v0 + tid] = acc[f];
}

// ---------------- per-diagram: gather, project, sort, level-3 signature -------------
__global__ __launch_bounds__(256) void k_diagram(const float* __restrict__ fv,
                                                 const int* __restrict__ dgm0,
                                                 const int* __restrict__ dgm1rel,
                                                 const int* __restrict__ dgm1ext,
                                                 const float* __restrict__ Wp,
                                                 const float* __restrict__ bp,
                                                 float* __restrict__ xbuf) {
  __shared__ float vals[640];
  __shared__ float ps[7 * 512];
  __shared__ float dXl[320][8];
  const int tid = threadIdx.x;
  const int bid = blockIdx.x;
  const int row = bid >> 1;
  const int c = bid & 1;
  const float* fvr = fv + (size_t)row * VV;

  for (int k = tid; k < 640; k += 256) {
    int idx;
    if (c == 0) idx = (k < 512) ? dgm0[(size_t)row * 512 + k] : dgm1rel[(size_t)row * 129 + (640 - k)];
    else        idx = dgm1ext[(size_t)row * 640 + k];
    vals[k] = fvr[idx];
  }
  __syncthreads();
  for (int q = tid; q < 7 * 512; q += 256) {
    int s = q >> 9, p = q & 511;
    float pv = 3.402823466e+38f;
    if (p < PP) pv = fmaf(Wp[2 * s + 1], vals[2 * p + 1], fmaf(Wp[2 * s], vals[2 * p], bp[s]));
    ps[s * 512 + p] = pv;
  }
  for (int k = 2; k <= 512; k <<= 1) {
    for (int j = k >> 1; j > 0; j >>= 1) {
      __syncthreads();
      for (int q = tid; q < 1792; q += 256) {
        int s = q >> 8, ip = q & 255;
        int i = ((ip & ~(j - 1)) << 1) | (ip & (j - 1));
        int p2 = i | j;
        float a = ps[s * 512 + i], b = ps[s * 512 + p2];
        bool up = ((i & k) == 0);
        if ((a > b) == up) { ps[s * 512 + i] = b; ps[s * 512 + p2] = a; }
      }
    }
  }
  __syncthreads();
  for (int q = tid; q < 319 * 8; q += 256) {
    int p = q >> 3, d = q & 7;
    dXl[p][d] = (d == 0) ? (1.0f / 51360.0f)
                         : ps[(d - 1) * 512 + p + 1] - ps[(d - 1) * 512 + p];
  }
  __syncthreads();
  if (tid < 64) {
    const int a = tid >> 3, b = tid & 7;
    float s1a = 0.f, s2r = 0.f;
    float s3r[8] = {0, 0, 0, 0, 0, 0, 0, 0};
    for (int p = 0; p < 319; ++p) {
      float4 dlo = *(const float4*)&dXl[p][0];
      float4 dhi = *(const float4*)&dXl[p][4];
      float dxa = dXl[p][a];
      float dxb = dXl[p][b];
      float coefA = fmaf(dxa, (1.f / 3.f), s1a);
      float w = fmaf(0.5f * dxb, coefA, s2r);
      s2r = fmaf(dxb, fmaf(0.5f, dxa, s1a), s2r);
      s3r[0] = fmaf(w, dlo.x, s3r[0]);
      s3r[1] = fmaf(w, dlo.y, s3r[1]);
      s3r[2] = fmaf(w, dlo.z, s3r[2]);
      s3r[3] = fmaf(w, dlo.w, s3r[3]);
      s3r[4] = fmaf(w, dhi.x, s3r[4]);
      s3r[5] = fmaf(w, dhi.y, s3r[5]);
      s3r[6] = fmaf(w, dhi.z, s3r[6]);
      s3r[7] = fmaf(w, dhi.w, s3r[7]);
      s1a += dxa;
    }
    const int l = row >> 3, ff = row & 7;
    float* xr = xbuf + (size_t)l * FINAL_W + ff * (2 * SIGLEN) + c * SIGLEN;
    if ((tid & 7) == 0) xr[a] = s1a;
    xr[8 + tid] = s2r;
    float* s3p = xr + 72 + tid * 8;
    *(float4*)(s3p + 0) = make_float4(s3r[0], s3r[1], s3r[2], s3r[3]);
    *(float4*)(s3p + 4) = make_float4(s3r[4], s3r[5], s3r[6], s3r[7]);
  }
}

// ---------------- final 9344-dot per l (fp64) --------------------------------------
__global__ __launch_bounds__(256) void k_rowdot(const float* __restrict__ xbuf,
                                                const float* __restrict__ Wf,
                                                const float* __restrict__ bf,
                                                double* __restrict__ outpre) {
  const int tid = threadIdx.x, l = blockIdx.x;
  const float* xr = xbuf + (size_t)l * FINAL_W;
  double acc = 0.0;
  for (int k = tid; k < FINAL_W; k += 256) acc += (double)xr[k] * (double)Wf[k];
  acc = wave_red(acc);
  __shared__ double r[4];
  int wave = tid >> 6, lane = tid & 63;
  if (lane == 0) r[wave] = acc;
  __syncthreads();
  if (tid == 0) outpre[l] = r[0] + r[1] + r[2] + r[3] + (double)bf[0];
}

// ---------------- final BN over 32 samples (fp64, eps-dominated) --------------------
__global__ __launch_bounds__(64) void k_bnfin(const double* __restrict__ outpre,
                                              const float* __restrict__ g,
                                              const float* __restrict__ beta,
                                              float* __restrict__ dout) {
  int i = threadIdx.x;
  double v = (i < 32) ? outpre[i] : 0.0;
  double s1 = wave_red(v);
  double s2 = wave_red(v * v);
  double mean = s1 * (1.0 / 32.0);
  double var = s2 * (1.0 / 32.0) - mean * mean;
  if (var < 0) var = 0;
  double inv = 1.0 / sqrt(var + 1e-5);
  if (i < 32) dout[i] = (float)((v - mean) * inv * (double)g[0] + (double)beta[0]);
}

extern "C" void kernel_launch(void* const* d_in, const int* in_sizes, int n_in,
                              void* d_out, int out_size, void* d_ws, size_t ws_size,
                              hipStream_t stream) {
  const float* eig     = (const float*)d_in[0];
  const float* eigsq   = (const float*)d_in[1];
  const int*   dgm0    = (const int*)d_in[2];
  const int*   dgm1rel = (const int*)d_in[3];
  const int*   dgm1ext = (const int*)d_in[4];
  const float* Win     = (const float*)d_in[5];
  // d_in[6] = mlp_bin: cancels exactly in input-layer BN
  const float* gin     = (const float*)d_in[7];
  const float* betain  = (const float*)d_in[8];
  const float* Wh      = (const float*)d_in[9];
  const float* bh      = (const float*)d_in[10];
  const float* gh      = (const float*)d_in[11];
  const float* betah   = (const float*)d_in[12];
  const float* Wout    = (const float*)d_in[13];
  const float* bout    = (const float*)d_in[14];
  const float* gout    = (const float*)d_in[15];
  const float* betaout = (const float*)d_in[16];
  const float* Wp      = (const float*)d_in[17];
  const float* bp      = (const float*)d_in[18];
  const float* Wfin    = (const float*)d_in[19];
  const float* bfin    = (const float*)d_in[20];
  const float* gfin    = (const float*)d_in[21];
  const float* betafin = (const float*)d_in[22];

  char* ws = (char*)d_ws;
  float*  Yt      = (float*)(ws);                  // 134,217,728 B : [F][HU][N], in-place reuse
  float*  evs_pre = (float*)(ws + 134217728u);     //   1,048,576 B : [F][N]
  float*  fv      = (float*)(ws + 135266304u);     //   2,097,152 B : [L*F][V]
  float*  xbuf    = (float*)(ws + 137363456u);     //   1,196,032 B : [L][9344]
  float*  sc1     = (float*)(ws + 138559488u);     // BN affine params
  float*  sh1     = sc1 + 1024;
  float*  sc2     = sc1 + 2048;
  float*  sh2     = sc1 + 3072;
  float*  sc3     = sc1 + 4096;
  float*  sh3     = sc1 + 4160;
  double* stats1  = (double*)(ws + 138576384u);    // [F*HU][2]
  double* stats2  = stats1 + 2048;                 // [F*HU][2]
  double* stats3  = stats1 + 4096;                 // [F][2]
  double* xstats  = stats1 + 4112;                 // [2]
  double* outpre  = stats1 + 4114;                 // [32]
  u16*    Whh     = (u16*)(ws + 138612736u);       // [F][2][HU][HU] bf16 limbs
  u16*    Whm     = (u16*)(ws + 139137024u);
  u16*    Whl     = (u16*)(ws + 139661312u);

  hipMemsetAsync(stats1, 0, 4114 * sizeof(double), stream);

  k_wsplit<<<1024, 256, 0, stream>>>(Wh, Whh, Whm, Whl, FF * 2 * HU * HU);
  k_xstats<<<1, 256, 0, stream>>>(eig, xstats);
  // hidden layer 0 (A from scalar x)
  k_mgemm<0><<<dim3(256, FF), 256, 0, stream>>>(eig, xstats, Win, gin, betain,
                                                nullptr, nullptr,
                                                Whh, Whm, Whl,
                                                bh, 256, Yt, stats1);
  k_fin<<<4, 256, 0, stream>>>(stats1, gh, betah, 128, 256, 1024, sc1, sh1);
  // hidden layer 1 (in-place on Yt), W limbs offset by one layer (HU*HU)
  k_mgemm<1><<<dim3(256, FF), 256, 0, stream>>>(Yt, nullptr, nullptr, nullptr, nullptr,
                                                sc1, sh1,
                                                Whh + HU * HU, Whm + HU * HU, Whl + HU * HU,
                                                bh + 128, 256, Yt, stats2);
  k_fin<<<4, 256, 0, stream>>>(stats2, gh + 128, betah + 128, 128, 256, 1024, sc2, sh2);
  k_outlayer<<<dim3(128, FF), 256, 0, stream>>>(Yt, sc2, sh2, Wout, bout, evs_pre, stats3);
  k_fin<<<1, 256, 0, stream>>>(stats3, gout, betaout, 1, 1, 8, sc3, sh3);
  k_einsum<<<dim3(8, 32), 256, 0, stream>>>(evs_pre, sc3, sh3, eigsq, fv);
  k_diagram<<<512, 256, 0, stream>>>(fv, dgm0, dgm1rel, dgm1ext, Wp, bp, xbuf);
  k_rowdot<<<32, 256, 0, stream>>>(xbuf, Wfin, bfin, outpre);
  k_bnfin<<<1, 64, 0, stream>>>(outpre, gfin, betafin, (float*)d_out);
}